// Round 10
// baseline (476.116 us; speedup 1.0000x reference)
//
#include <hip/hip_runtime.h>
#include <cstdint>
#include <cstddef>

#define B_    2
#define T_    2048
#define DIM_  2048
#define H_    32
#define HKV_  8
#define HD_   64
#define NQKV  3072   // 2048 q + 512 k + 512 v

typedef __attribute__((ext_vector_type(8))) __bf16 bf16x8;
typedef __attribute__((ext_vector_type(4))) float  f32x4;

typedef __attribute__((address_space(1))) void GV;
typedef __attribute__((address_space(3))) void LV;

__device__ __forceinline__ void gload_lds16(const void* g, void* l) {
  __builtin_amdgcn_global_load_lds((const GV*)g, (LV*)l, 16, 0, 0);
}

__device__ __forceinline__ unsigned short f2bf(float f) {
  union { float f; unsigned int u; } c;
  c.f = f;
  unsigned int r = (c.u + 0x7FFFu + ((c.u >> 16) & 1u)) >> 16;
  return (unsigned short)r;
}

__device__ __forceinline__ unsigned int cvt_pk_bf16(float lo, float hi) {
  unsigned int r;
  asm("v_cvt_pk_bf16_f32 %0, %1, %2" : "=v"(r) : "v"(lo), "v"(hi));
  return r;
}

// ---------------------------------------------------------------------------
// Transpose f32 [R][C] -> bf16 [C][R]
// ---------------------------------------------------------------------------
__global__ __launch_bounds__(256) void k_transpose_w(const float* __restrict__ in,
                                                     unsigned short* __restrict__ out,
                                                     int R, int C) {
  __shared__ float tile[32][33];
  int c0 = blockIdx.x * 32, r0 = blockIdx.y * 32;
  int tx = threadIdx.x, ty = threadIdx.y;  // 32 x 8
#pragma unroll
  for (int i = 0; i < 32; i += 8)
    tile[ty + i][tx] = in[(size_t)(r0 + ty + i) * C + c0 + tx];
  __syncthreads();
#pragma unroll
  for (int i = 0; i < 32; i += 8)
    out[(size_t)(c0 + ty + i) * R + r0 + tx] = f2bf(tile[tx][ty + i]);
}

// ---------------------------------------------------------------------------
// f32 -> bf16 elementwise (vectorized x4)
// ---------------------------------------------------------------------------
__global__ __launch_bounds__(256) void k_cvt_bf16(const float* __restrict__ in,
                                                  unsigned short* __restrict__ out, int n4) {
  int i = blockIdx.x * blockDim.x + threadIdx.x;
  if (i >= n4) return;
  float4 v = reinterpret_cast<const float4*>(in)[i];
  ushort4 o;
  o.x = f2bf(v.x); o.y = f2bf(v.y); o.z = f2bf(v.z); o.w = f2bf(v.w);
  reinterpret_cast<ushort4*>(out)[i] = o;
}

// ---------------------------------------------------------------------------
// bf16 GEMM: C[M][N] f32 = A[M][K] * B[N][K]^T   (both bf16, K-contiguous)
// 128x128 tile, BK=32, 4 waves, 4x4 16x16x32 MFMA fragments per wave.
// ---------------------------------------------------------------------------
__global__ __launch_bounds__(256, 2) void k_gemm_bt(const unsigned short* __restrict__ A,
                                                    const unsigned short* __restrict__ Bm,
                                                    float* __restrict__ C,
                                                    int M, int N, int K) {
  __shared__ unsigned short Asl[128 * 32];
  __shared__ unsigned short Bsl[128 * 32];
  const int m0 = blockIdx.y * 128, n0 = blockIdx.x * 128;
  const int tid = threadIdx.x;
  const int l = tid & 63, wid = tid >> 6;
  const int wr = wid >> 1, wc = wid & 1;
  const int lc = l & 15, lr = l >> 4;
  const int srow = tid >> 2;         // 0..63 staging row
  const int sc8 = (tid & 3) * 8;     // staging k-offset (elements)
  const unsigned short* Ag = A + (size_t)m0 * K;
  const unsigned short* Bg = Bm + (size_t)n0 * K;

  f32x4 acc[4][4] = {};

  for (int k0 = 0; k0 < K; k0 += 32) {
    __syncthreads();
    gload_lds16(Ag + (size_t)srow * K + k0 + sc8,        &Asl[srow * 32 + sc8]);
    gload_lds16(Ag + (size_t)(srow + 64) * K + k0 + sc8, &Asl[(srow + 64) * 32 + sc8]);
    gload_lds16(Bg + (size_t)srow * K + k0 + sc8,        &Bsl[srow * 32 + sc8]);
    gload_lds16(Bg + (size_t)(srow + 64) * K + k0 + sc8, &Bsl[(srow + 64) * 32 + sc8]);
    __syncthreads();
    bf16x8 af[4], bfr[4];
#pragma unroll
    for (int mi = 0; mi < 4; ++mi)
      af[mi] = *(const bf16x8*)&Asl[(wr * 64 + mi * 16 + lc) * 32 + lr * 8];
#pragma unroll
    for (int ni = 0; ni < 4; ++ni)
      bfr[ni] = *(const bf16x8*)&Bsl[(wc * 64 + ni * 16 + lc) * 32 + lr * 8];
#pragma unroll
    for (int mi = 0; mi < 4; ++mi)
#pragma unroll
      for (int ni = 0; ni < 4; ++ni)
        acc[mi][ni] = __builtin_amdgcn_mfma_f32_16x16x32_bf16(af[mi], bfr[ni], acc[mi][ni], 0, 0, 0);
  }

#pragma unroll
  for (int mi = 0; mi < 4; ++mi)
#pragma unroll
    for (int ni = 0; ni < 4; ++ni) {
      int row = m0 + wr * 64 + mi * 16 + lr * 4;
      int col = n0 + wc * 64 + ni * 16 + lc;
      float* Cp = C + (size_t)row * N + col;
#pragma unroll
      for (int rr = 0; rr < 4; ++rr) Cp[(size_t)rr * N] = acc[mi][ni][rr];
    }
}

// ---------------------------------------------------------------------------
// RoPE on Q: qkv f32 [B*T][3072] cols [0,2048) -> qb bf16 [B][H][T][64]
// ---------------------------------------------------------------------------
__global__ __launch_bounds__(256) void k_rope_q(const float* __restrict__ qkv,
                                                const float* __restrict__ fc,
                                                const float* __restrict__ fs,
                                                unsigned short* __restrict__ qb) {
  int tid = blockIdx.x * 256 + threadIdx.x;   // < B*T*H*32 = 4,194,304
  int i = tid & 31;
  int h = (tid >> 5) & 31;
  int bt = tid >> 10;                          // 0..4095
  int b = bt >> 11, t = bt & 2047;
  float2 x = reinterpret_cast<const float2*>(qkv + (size_t)bt * NQKV + h * 64)[i];
  float c = fc[t * 32 + i], s = fs[t * 32 + i];
  ushort2 o;
  o.x = f2bf(x.x * c - x.y * s);
  o.y = f2bf(x.x * s + x.y * c);
  reinterpret_cast<ushort2*>(qb + ((size_t)(b * H_ + h) * T_ + t) * HD_)[i] = o;
}

__global__ __launch_bounds__(256) void k_rope_k(const float* __restrict__ qkv,
                                                const float* __restrict__ fc,
                                                const float* __restrict__ fs,
                                                unsigned short* __restrict__ kb) {
  int tid = blockIdx.x * 256 + threadIdx.x;   // < B*T*HKV*32 = 1,048,576
  int i = tid & 31;
  int hk = (tid >> 5) & 7;
  int bt = tid >> 8;
  int b = bt >> 11, t = bt & 2047;
  float2 x = reinterpret_cast<const float2*>(qkv + (size_t)bt * NQKV + 2048 + hk * 64)[i];
  float c = fc[t * 32 + i], s = fs[t * 32 + i];
  ushort2 o;
  o.x = f2bf(x.x * c - x.y * s);
  o.y = f2bf(x.x * s + x.y * c);
  reinterpret_cast<ushort2*>(kb + ((size_t)(b * HKV_ + hk) * T_ + t) * HD_)[i] = o;
}

// ---------------------------------------------------------------------------
// V: qkv f32 cols [2560,3072) -> vt bf16 [B][HKV][64 d][T] (transposed)
// ---------------------------------------------------------------------------
__global__ __launch_bounds__(256) void k_vtrans(const float* __restrict__ qkv,
                                                unsigned short* __restrict__ vt) {
  __shared__ unsigned short tile[64][65];
  int t0 = blockIdx.x * 64;
  int bh = blockIdx.y;                     // b*HKV + hk
  int tx = threadIdx.x, ty = threadIdx.y;  // 64 x 4
  int b = bh >> 3, hk = bh & 7;
  int colbase = 2560 + hk * 64;
#pragma unroll
  for (int tt = 0; tt < 16; ++tt) {
    int tr = tt * 4 + ty;
    tile[tr][tx] = f2bf(qkv[(size_t)(b * T_ + t0 + tr) * NQKV + colbase + tx]);
  }
  __syncthreads();
  size_t obase = (size_t)bh * 64 * T_;
#pragma unroll
  for (int tt = 0; tt < 16; ++tt) {
    int d = tt * 4 + ty;
    vt[obase + (size_t)d * T_ + t0 + tx] = tile[tx][d];
  }
}

// ---------------------------------------------------------------------------
// Causal flash attention — barrier-free, zero-LDS, swapped-QK in-reg softmax,
// causal work pairing + K/V prefetch.  ONE task per block (grid 1024).
//
// bid&7 = hk (XCD L2 clustering).  slot=bid>>3: hrem=slot&3, s_=slot>>2;
// tsk=s_&1, p = tsk ? 15-(s_>>1) : (s_>>1).  Task = (b=tsk, h=hk*4+hrem,
// pair p): q-blocks qlo=p, qhi=31-p (64-row blocks); every wave owns one
// 16-row fragment of each; K/V tiles shared while kvt<=qlo.
//
// launch_bounds (256,2): rounds 7/9 failed with 2nd arg 4/3 (tightened VGPR
// cap -> suspected regalloc/spill miscompile); round 6 passed with (256,2)
// and compiled to 116 VGPR, which already permits 4 blocks/CU residency.
// ---------------------------------------------------------------------------
__global__ __launch_bounds__(256, 2) void k_flash(const unsigned short* __restrict__ Q,
                                                  const unsigned short* __restrict__ Kt,
                                                  const unsigned short* __restrict__ Vt,
                                                  unsigned short* __restrict__ O) {
  const int bid = blockIdx.x;
  const int hk = bid & 7;
  const int slot = bid >> 3;       // 0..127
  const int s_ = slot >> 2;        // 0..31
  const int hrem = slot & 3;
  const int h = hk * 4 + hrem;
  const int tsk = s_ & 1;
  const int p = tsk ? (15 - (s_ >> 1)) : (s_ >> 1);
  const int b = tsk;
  const int qlo = p, qhi = 31 - p;

  const int tid = threadIdx.x, w = tid >> 6, l = tid & 63;
  const int lr = l >> 4, lc = l & 15;
  const float SC = 0.125f * 1.44269504f;   // 1/sqrt(64) * log2(e)
  const int srcA = lc + 32 * (lr & 1);     // P-regroup source lane
  const bool hi = (lr >= 2);

  const size_t qbase = (size_t)(b * H_ + h) * T_ * HD_;
  const size_t kbase = (size_t)(b * HKV_ + hk) * T_ * HD_;
  const size_t vbase = (size_t)(b * HKV_ + hk) * HD_ * T_;
  const int rowL = qlo * 64 + w * 16;  // + lc
  const int rowH = qhi * 64 + w * 16;

  // Q fragments (B-operand): col=lc -> Q row rowX+lc, k = ks*32+lr*8+j
  bf16x8 qL[2], qH[2];
#pragma unroll
  for (int ks = 0; ks < 2; ++ks) {
    qL[ks] = *(const bf16x8*)&Q[qbase + (size_t)(rowL + lc) * HD_ + ks * 32 + lr * 8];
    qH[ks] = *(const bf16x8*)&Q[qbase + (size_t)(rowH + lc) * HD_ + ks * 32 + lr * 8];
  }

  f32x4 oL[4] = {}, oH[4] = {};
  float mL = -1e30f, mH = -1e30f, lsL = 0.f, lsH = 0.f;

  auto loadK = [&](bf16x8 (&kf)[2][4], int kv0x) {
#pragma unroll
    for (int ks = 0; ks < 2; ++ks)
#pragma unroll
      for (int ni = 0; ni < 4; ++ni)
        kf[ks][ni] = *(const bf16x8*)&Kt[kbase + (size_t)(kv0x + ni * 16 + lc) * HD_ + ks * 32 + lr * 8];
  };

  // softmax on a raw score tile; updates (m, ls, o), emits PV A-fragments pa
  auto softmax = [&](f32x4 (&s)[4], int kv0, int qrow0, bool diag,
                     float& m, float& ls, f32x4 (&o)[4], bf16x8 (&pa)[2]) {
    if (diag) {
      const int qcol = qrow0 + lc;
#pragma unroll
      for (int ni = 0; ni < 4; ++ni)
#pragma unroll
        for (int r = 0; r < 4; ++r)
          if (kv0 + ni * 16 + lr * 4 + r > qcol) s[ni][r] = -1e30f;
    }
    float x0 = fmaxf(fmaxf(s[0][0], s[0][1]), fmaxf(s[0][2], s[0][3]));
    float x1 = fmaxf(fmaxf(s[1][0], s[1][1]), fmaxf(s[1][2], s[1][3]));
    float x2 = fmaxf(fmaxf(s[2][0], s[2][1]), fmaxf(s[2][2], s[2][3]));
    float x3 = fmaxf(fmaxf(s[3][0], s[3][1]), fmaxf(s[3][2], s[3][3]));
    float pm = fmaxf(fmaxf(x0, x1), fmaxf(x2, x3));
    pm = fmaxf(pm, __shfl_xor(pm, 16));
    pm = fmaxf(pm, __shfl_xor(pm, 32));
    const float pms = pm * SC;
    // defer-max (T13, log2 domain, THR=8)
    if (!__all(pms <= m + 8.f)) {
      float mn = fmaxf(m, pms);
      float al = __builtin_amdgcn_exp2f(m - mn);
      m = mn;
      ls *= al;
      float av0 = __shfl(al, lr * 4 + 0);
      float av1 = __shfl(al, lr * 4 + 1);
      float av2 = __shfl(al, lr * 4 + 2);
      float av3 = __shfl(al, lr * 4 + 3);
#pragma unroll
      for (int di = 0; di < 4; ++di) {
        o[di][0] *= av0; o[di][1] *= av1;
        o[di][2] *= av2; o[di][3] *= av3;
      }
    }
    float ps = 0.f;
    unsigned int P01[4], P23[4];
#pragma unroll
    for (int ni = 0; ni < 4; ++ni) {
      float p0 = __builtin_amdgcn_exp2f(__builtin_fmaf(s[ni][0], SC, -m));
      float p1 = __builtin_amdgcn_exp2f(__builtin_fmaf(s[ni][1], SC, -m));
      float p2 = __builtin_amdgcn_exp2f(__builtin_fmaf(s[ni][2], SC, -m));
      float p3 = __builtin_amdgcn_exp2f(__builtin_fmaf(s[ni][3], SC, -m));
      ps += (p0 + p1) + (p2 + p3);
      P01[ni] = cvt_pk_bf16(p0, p1);
      P23[ni] = cvt_pk_bf16(p2, p3);
    }
    ps += __shfl_xor(ps, 16);
    ps += __shfl_xor(ps, 32);
    ls += ps;
    // regroup: lane(lc,lr) needs K-chunk ks*32+lr*8..+7 of Q-row lc
#pragma unroll
    for (int ks = 0; ks < 2; ++ks) {
      unsigned int a0 = __shfl(P01[2 * ks], srcA);
      unsigned int a1 = __shfl(P23[2 * ks], srcA);
      unsigned int a2 = __shfl(P01[2 * ks], srcA + 16);
      unsigned int a3 = __shfl(P23[2 * ks], srcA + 16);
      unsigned int b0 = __shfl(P01[2 * ks + 1], srcA);
      unsigned int b1 = __shfl(P23[2 * ks + 1], srcA);
      unsigned int b2 = __shfl(P01[2 * ks + 1], srcA + 16);
      unsigned int b3 = __shfl(P23[2 * ks + 1], srcA + 16);
      union { unsigned int u[4]; bf16x8 v; } pw;
      pw.u[0] = hi ? b0 : a0;
      pw.u[1] = hi ? b1 : a1;
      pw.u[2] = hi ? b2 : a2;
      pw.u[3] = hi ? b3 : a3;
      pa[ks] = pw.v;
    }
  };

  bf16x8 kf[2][4];
  loadK(kf, 0);  // prologue

  for (int kvt = 0; kvt <= qhi; ++kvt) {
    const int kv0 = kvt * 64;
    const bool doL = (kvt <= qlo);

    // V fragments issued early — hide under QK + softmax
    bf16x8 vf[2][4];
#pragma unroll
    for (int ks = 0; ks < 2; ++ks)
#pragma unroll
      for (int di = 0; di < 4; ++di)
        vf[ks][di] = *(const bf16x8*)&Vt[vbase + (size_t)(di * 16 + lc) * T_ + kv0 + ks * 32 + lr * 8];

    // QK^T for H fragment (kf prefetched last iteration)
    f32x4 s[4] = {};
    __builtin_amdgcn_s_setprio(1);
#pragma unroll
    for (int ks = 0; ks < 2; ++ks)
#pragma unroll
      for (int ni = 0; ni < 4; ++ni)
        s[ni] = __builtin_amdgcn_mfma_f32_16x16x32_bf16(kf[ks][ni], qH[ks], s[ni], 0, 0, 0);
    __builtin_amdgcn_s_setprio(0);

    bf16x8 paH[2], paL[2];
    softmax(s, kv0, rowH, kvt == qhi, mH, lsH, oH, paH);

    if (doL) {
      f32x4 s2[4] = {};
      __builtin_amdgcn_s_setprio(1);
#pragma unroll
      for (int ks = 0; ks < 2; ++ks)
#pragma unroll
        for (int ni = 0; ni < 4; ++ni)
          s2[ni] = __builtin_amdgcn_mfma_f32_16x16x32_bf16(kf[ks][ni], qL[ks], s2[ni], 0, 0, 0);
      __builtin_amdgcn_s_setprio(0);
      if (kvt < qhi) loadK(kf, kv0 + 64);  // prefetch next K tile
      softmax(s2, kv0, rowL, kvt == qlo, mL, lsL, oL, paL);
    } else {
      if (kvt < qhi) loadK(kf, kv0 + 64);
    }

    // PV
    __builtin_amdgcn_s_setprio(1);
#pragma unroll
    for (int ks = 0; ks < 2; ++ks)
#pragma unroll
      for (int di = 0; di < 4; ++di)
        oH[di] = __builtin_amdgcn_mfma_f32_16x16x32_bf16(paH[ks], vf[ks][di], oH[di], 0, 0, 0);
    if (doL) {
#pragma unroll
      for (int ks = 0; ks < 2; ++ks)
#pragma unroll
        for (int di = 0; di < 4; ++di)
          oL[di] = __builtin_amdgcn_mfma_f32_16x16x32_bf16(paL[ks], vf[ks][di], oL[di], 0, 0, 0);
    }
    __builtin_amdgcn_s_setprio(0);
  }

  // epilogue: rows lr*4+r ; lsum lives lc-indexed in lanes 0..15
  auto epi = [&](f32x4 (&o)[4], float ls, int row0) {
    float i0 = 1.f / __shfl(ls, lr * 4 + 0);
    float i1 = 1.f / __shfl(ls, lr * 4 + 1);
    float i2 = 1.f / __shfl(ls, lr * 4 + 2);
    float i3 = 1.f / __shfl(ls, lr * 4 + 3);
#pragma unroll
    for (int di = 0; di < 4; ++di) {
      int row = row0 + lr * 4;
      size_t base = (size_t)(b * T_ + row) * DIM_ + h * 64 + di * 16 + lc;
      O[base]            = f2bf(o[di][0] * i0);
      O[base + DIM_]     = f2bf(o[di][1] * i1);
      O[base + 2 * DIM_] = f2bf(o[di][2] * i2);
      O[base + 3 * DIM_] = f2bf(o[di][3] * i3);
    }
  };
  epi(oH, lsH, rowH);
  epi(oL, lsL, rowL);
}

// ---------------------------------------------------------------------------
// Orchestration
// ---------------------------------------------------------------------------
extern "C" void kernel_launch(void* const* d_in, const int* in_sizes, int n_in,
                              void* d_out, int out_size, void* d_ws, size_t ws_size,
                              hipStream_t stream) {
  const float* x  = (const float*)d_in[0];
  const float* fc = (const float*)d_in[1];
  const float* fs = (const float*)d_in[2];
  const float* wq = (const float*)d_in[3];
  const float* wk = (const float*)d_in[4];
  const float* wv = (const float*)d_in[5];
  const float* wo = (const float*)d_in[6];
  float* out = (float*)d_out;
  char* ws = (char*)d_ws;

  // workspace layout (bytes) — round-6 layout verbatim
  unsigned short* xb   = (unsigned short*)(ws);                   // 16 MB  x bf16 [4096][2048]
  unsigned short* wT   = (unsigned short*)(ws + 16777216);        // 12 MB  wqkv^T bf16 [3072][2048]
  unsigned short* woT  = (unsigned short*)(ws + 29360128);        //  8 MB  wo^T bf16 [2048][2048]
  float*          qkv  = (float*)(ws + 37748736);                 // 50 MB  qkv f32 [4096][3072]
  unsigned short* qb   = (unsigned short*)(ws + 88080384);        // 16 MB  q bf16 [B][H][T][64]
  unsigned short* kb   = (unsigned short*)(ws + 104857600);       //  4 MB  k bf16 [B][HKV][T][64]
  unsigned short* vt   = (unsigned short*)(ws + 109051904);       //  4 MB  v bf16 [B][HKV][64][T]
  unsigned short* attn = (unsigned short*)(ws + 37748736);        // alias over qkv (dead by then)

  dim3 tb(32, 8);
  k_transpose_w<<<dim3(64, 64), tb, 0, stream>>>(wq, wT, 2048, 2048);
  k_transpose_w<<<dim3(16, 64), tb, 0, stream>>>(wk, wT + (size_t)2048 * 2048, 2048, 512);
  k_transpose_w<<<dim3(16, 64), tb, 0, stream>>>(wv, wT + (size_t)2560 * 2048, 2048, 512);
  k_transpose_w<<<dim3(64, 64), tb, 0, stream>>>(wo, woT, 2048, 2048);
  k_cvt_bf16<<<8192, 256, 0, stream>>>(x, xb, 2097152);

  k_gemm_bt<<<dim3(NQKV / 128, 4096 / 128), 256, 0, stream>>>(xb, wT, qkv, 4096, NQKV, 2048);

  k_rope_q<<<16384, 256, 0, stream>>>(qkv, fc, fs, qb);
  k_rope_k<<<4096, 256, 0, stream>>>(qkv, fc, fs, kb);
  k_vtrans<<<dim3(T_ / 64, B_ * HKV_), dim3(64, 4), 0, stream>>>(qkv, vt);

  k_flash<<<1024, 256, 0, stream>>>(qb, kb, vt, attn);

  k_gemm_bt<<<dim3(2048 / 128, 4096 / 128), 256, 0, stream>>>(attn, woT, out, 4096, 2048, 2048);
}

// Round 13
// 425.792 us; speedup vs baseline: 1.1182x; 1.1182x over previous
//
#include <hip/hip_runtime.h>
#include <cstdint>
#include <cstddef>

#define B_    2
#define T_    2048
#define DIM_  2048
#define H_    32
#define HKV_  8
#define HD_   64
#define NQKV  3072   // 2048 q + 512 k + 512 v

typedef __attribute__((ext_vector_type(8))) __bf16 bf16x8;
typedef __attribute__((ext_vector_type(4))) float  f32x4;

typedef __attribute__((address_space(1))) void GV;
typedef __attribute__((address_space(3))) void LV;

__device__ __forceinline__ void gload_lds16(const void* g, void* l) {
  __builtin_amdgcn_global_load_lds((const GV*)g, (LV*)l, 16, 0, 0);
}

__device__ __forceinline__ unsigned short f2bf(float f) {
  union { float f; unsigned int u; } c;
  c.f = f;
  unsigned int r = (c.u + 0x7FFFu + ((c.u >> 16) & 1u)) >> 16;
  return (unsigned short)r;
}

__device__ __forceinline__ unsigned int cvt_pk_bf16(float lo, float hi) {
  unsigned int r;
  asm("v_cvt_pk_bf16_f32 %0, %1, %2" : "=v"(r) : "v"(lo), "v"(hi));
  return r;
}

__device__ __forceinline__ float bflo(unsigned int u) {
  union { unsigned int i; float f; } c; c.i = u << 16; return c.f;
}
__device__ __forceinline__ float bfhi(unsigned int u) {
  union { unsigned int i; float f; } c; c.i = u & 0xffff0000u; return c.f;
}

// ---------------------------------------------------------------------------
// Transpose f32 [R][C] -> bf16 [C][R]
// ---------------------------------------------------------------------------
__global__ __launch_bounds__(256) void k_transpose_w(const float* __restrict__ in,
                                                     unsigned short* __restrict__ out,
                                                     int R, int C) {
  __shared__ float tile[32][33];
  int c0 = blockIdx.x * 32, r0 = blockIdx.y * 32;
  int tx = threadIdx.x, ty = threadIdx.y;  // 32 x 8
#pragma unroll
  for (int i = 0; i < 32; i += 8)
    tile[ty + i][tx] = in[(size_t)(r0 + ty + i) * C + c0 + tx];
  __syncthreads();
#pragma unroll
  for (int i = 0; i < 32; i += 8)
    out[(size_t)(c0 + ty + i) * R + r0 + tx] = f2bf(tile[tx][ty + i]);
}

// ---------------------------------------------------------------------------
// f32 -> bf16 elementwise (vectorized x4)
// ---------------------------------------------------------------------------
__global__ __launch_bounds__(256) void k_cvt_bf16(const float* __restrict__ in,
                                                  unsigned short* __restrict__ out, int n4) {
  int i = blockIdx.x * blockDim.x + threadIdx.x;
  if (i >= n4) return;
  float4 v = reinterpret_cast<const float4*>(in)[i];
  ushort4 o;
  o.x = f2bf(v.x); o.y = f2bf(v.y); o.z = f2bf(v.z); o.w = f2bf(v.w);
  reinterpret_cast<ushort4*>(out)[i] = o;
}

// ---------------------------------------------------------------------------
// bf16 GEMM: C[M][N] = A[M][K] * B[N][K]^T  (bf16 in, f32 or bf16 out)
// 128x128 tile, BK=32, 4 waves, 4x4 16x16x32 MFMA fragments per wave.
// ---------------------------------------------------------------------------
template <bool OBF>
__global__ __launch_bounds__(256, 2) void k_gemm_bt(const unsigned short* __restrict__ A,
                                                    const unsigned short* __restrict__ Bm,
                                                    void* __restrict__ Cv,
                                                    int M, int N, int K) {
  __shared__ unsigned short Asl[128 * 32];
  __shared__ unsigned short Bsl[128 * 32];
  const int m0 = blockIdx.y * 128, n0 = blockIdx.x * 128;
  const int tid = threadIdx.x;
  const int l = tid & 63, wid = tid >> 6;
  const int wr = wid >> 1, wc = wid & 1;
  const int lc = l & 15, lr = l >> 4;
  const int srow = tid >> 2;         // 0..63 staging row
  const int sc8 = (tid & 3) * 8;     // staging k-offset (elements)
  const unsigned short* Ag = A + (size_t)m0 * K;
  const unsigned short* Bg = Bm + (size_t)n0 * K;

  f32x4 acc[4][4] = {};

  for (int k0 = 0; k0 < K; k0 += 32) {
    __syncthreads();
    gload_lds16(Ag + (size_t)srow * K + k0 + sc8,        &Asl[srow * 32 + sc8]);
    gload_lds16(Ag + (size_t)(srow + 64) * K + k0 + sc8, &Asl[(srow + 64) * 32 + sc8]);
    gload_lds16(Bg + (size_t)srow * K + k0 + sc8,        &Bsl[srow * 32 + sc8]);
    gload_lds16(Bg + (size_t)(srow + 64) * K + k0 + sc8, &Bsl[(srow + 64) * 32 + sc8]);
    __syncthreads();
    bf16x8 af[4], bfr[4];
#pragma unroll
    for (int mi = 0; mi < 4; ++mi)
      af[mi] = *(const bf16x8*)&Asl[(wr * 64 + mi * 16 + lc) * 32 + lr * 8];
#pragma unroll
    for (int ni = 0; ni < 4; ++ni)
      bfr[ni] = *(const bf16x8*)&Bsl[(wc * 64 + ni * 16 + lc) * 32 + lr * 8];
#pragma unroll
    for (int mi = 0; mi < 4; ++mi)
#pragma unroll
      for (int ni = 0; ni < 4; ++ni)
        acc[mi][ni] = __builtin_amdgcn_mfma_f32_16x16x32_bf16(af[mi], bfr[ni], acc[mi][ni], 0, 0, 0);
  }

#pragma unroll
  for (int mi = 0; mi < 4; ++mi)
#pragma unroll
    for (int ni = 0; ni < 4; ++ni) {
      int row = m0 + wr * 64 + mi * 16 + lr * 4;
      int col = n0 + wc * 64 + ni * 16 + lc;
      if constexpr (OBF) {
        unsigned short* Cp = (unsigned short*)Cv + (size_t)row * N + col;
#pragma unroll
        for (int rr = 0; rr < 4; ++rr) Cp[(size_t)rr * N] = f2bf(acc[mi][ni][rr]);
      } else {
        float* Cp = (float*)Cv + (size_t)row * N + col;
#pragma unroll
        for (int rr = 0; rr < 4; ++rr) Cp[(size_t)rr * N] = acc[mi][ni][rr];
      }
    }
}

// ---------------------------------------------------------------------------
// RoPE on Q: qkv bf16 [B*T][3072] cols [0,2048) -> qb bf16 [B][H][T][64]
// one thread per (bt, h, group of 4 pairs) — 16B load / 16B store
// ---------------------------------------------------------------------------
__global__ __launch_bounds__(256) void k_rope_q(const unsigned short* __restrict__ qkvb,
                                                const float* __restrict__ fc,
                                                const float* __restrict__ fs,
                                                unsigned short* __restrict__ qb) {
  int tid = blockIdx.x * 256 + threadIdx.x;   // < 4096*32*8 = 1,048,576
  int g = tid & 7;
  int h = (tid >> 3) & 31;
  int bt = tid >> 8;
  int b = bt >> 11, t = bt & 2047;
  uint4 v = *reinterpret_cast<const uint4*>(qkvb + (size_t)bt * NQKV + h * 64 + g * 8);
  float4 c = *reinterpret_cast<const float4*>(fc + t * 32 + g * 4);
  float4 s = *reinterpret_cast<const float4*>(fs + t * 32 + g * 4);
  uint4 o;
  { float re = bflo(v.x), im = bfhi(v.x);
    o.x = (unsigned int)f2bf(re * c.x - im * s.x) | ((unsigned int)f2bf(re * s.x + im * c.x) << 16); }
  { float re = bflo(v.y), im = bfhi(v.y);
    o.y = (unsigned int)f2bf(re * c.y - im * s.y) | ((unsigned int)f2bf(re * s.y + im * c.y) << 16); }
  { float re = bflo(v.z), im = bfhi(v.z);
    o.z = (unsigned int)f2bf(re * c.z - im * s.z) | ((unsigned int)f2bf(re * s.z + im * c.z) << 16); }
  { float re = bflo(v.w), im = bfhi(v.w);
    o.w = (unsigned int)f2bf(re * c.w - im * s.w) | ((unsigned int)f2bf(re * s.w + im * c.w) << 16); }
  *reinterpret_cast<uint4*>(qb + ((size_t)(b * H_ + h) * T_ + t) * HD_ + g * 8) = o;
}

__global__ __launch_bounds__(256) void k_rope_k(const unsigned short* __restrict__ qkvb,
                                                const float* __restrict__ fc,
                                                const float* __restrict__ fs,
                                                unsigned short* __restrict__ kb) {
  int tid = blockIdx.x * 256 + threadIdx.x;   // < 4096*8*8 = 262,144
  int g = tid & 7;
  int hk = (tid >> 3) & 7;
  int bt = tid >> 6;
  int b = bt >> 11, t = bt & 2047;
  uint4 v = *reinterpret_cast<const uint4*>(qkvb + (size_t)bt * NQKV + 2048 + hk * 64 + g * 8);
  float4 c = *reinterpret_cast<const float4*>(fc + t * 32 + g * 4);
  float4 s = *reinterpret_cast<const float4*>(fs + t * 32 + g * 4);
  uint4 o;
  { float re = bflo(v.x), im = bfhi(v.x);
    o.x = (unsigned int)f2bf(re * c.x - im * s.x) | ((unsigned int)f2bf(re * s.x + im * c.x) << 16); }
  { float re = bflo(v.y), im = bfhi(v.y);
    o.y = (unsigned int)f2bf(re * c.y - im * s.y) | ((unsigned int)f2bf(re * s.y + im * c.y) << 16); }
  { float re = bflo(v.z), im = bfhi(v.z);
    o.z = (unsigned int)f2bf(re * c.z - im * s.z) | ((unsigned int)f2bf(re * s.z + im * c.z) << 16); }
  { float re = bflo(v.w), im = bfhi(v.w);
    o.w = (unsigned int)f2bf(re * c.w - im * s.w) | ((unsigned int)f2bf(re * s.w + im * c.w) << 16); }
  *reinterpret_cast<uint4*>(kb + ((size_t)(b * HKV_ + hk) * T_ + t) * HD_ + g * 8) = o;
}

// ---------------------------------------------------------------------------
// V: qkv bf16 cols [2560,3072) -> vt bf16 [B][HKV][64 d][T] (transposed)
// ---------------------------------------------------------------------------
__global__ __launch_bounds__(256) void k_vtrans(const unsigned short* __restrict__ qkvb,
                                                unsigned short* __restrict__ vt) {
  __shared__ unsigned short tile[64][65];
  int t0 = blockIdx.x * 64;
  int bh = blockIdx.y;                     // b*HKV + hk
  int tx = threadIdx.x, ty = threadIdx.y;  // 64 x 4
  int b = bh >> 3, hk = bh & 7;
  int colbase = 2560 + hk * 64;
#pragma unroll
  for (int tt = 0; tt < 16; ++tt) {
    int tr = tt * 4 + ty;
    tile[tr][tx] = qkvb[(size_t)(b * T_ + t0 + tr) * NQKV + colbase + tx];
  }
  __syncthreads();
  size_t obase = (size_t)bh * 64 * T_;
#pragma unroll
  for (int tt = 0; tt < 16; ++tt) {
    int d = tt * 4 + ty;
    vt[obase + (size_t)d * T_ + t0 + tx] = tile[tx][d];
  }
}

// ---------------------------------------------------------------------------
// Causal flash attention — round-6 fused version VERBATIM (known-good,
// 192 us).  Barrier-free, zero-LDS, swapped-QK in-reg softmax, causal work
// pairing + K/V prefetch.  Grid 512; per block two complementary tasks
// (p=pq,b=0) and (p=15-pq,b=1); per-block trips = 49 machine-uniform.
// NOTE: __launch_bounds__ 2nd arg must stay <=2 — values 3/4 miscompile
// this body (rounds 7/9: ls-collapse absmax ~6e30; round 10 bisect).
// ---------------------------------------------------------------------------
__global__ __launch_bounds__(256, 2) void k_flash(const unsigned short* __restrict__ Q,
                                                  const unsigned short* __restrict__ Kt,
                                                  const unsigned short* __restrict__ Vt,
                                                  unsigned short* __restrict__ O) {
  const int bid = blockIdx.x;
  const int hk = bid & 7;
  const int slot = bid >> 3;       // 0..63
  const int pq = slot & 15;        // pair index
  const int hrem = slot >> 4;      // 0..3
  const int h = hk * 4 + hrem;

  const int tid = threadIdx.x, w = tid >> 6, l = tid & 63;
  const int lr = l >> 4, lc = l & 15;
  const float SC = 0.125f * 1.44269504f;   // 1/sqrt(64) * log2(e)
  const int srcA = lc + 32 * (lr & 1);     // P-regroup source lane
  const bool hi = (lr >= 2);

  for (int tsk = 0; tsk < 2; ++tsk) {
    const int b = tsk;
    const int p = tsk ? (15 - pq) : pq;
    const int qlo = p, qhi = 31 - p;

    const size_t qbase = (size_t)(b * H_ + h) * T_ * HD_;
    const size_t kbase = (size_t)(b * HKV_ + hk) * T_ * HD_;
    const size_t vbase = (size_t)(b * HKV_ + hk) * HD_ * T_;
    const int rowL = qlo * 64 + w * 16;  // + lc
    const int rowH = qhi * 64 + w * 16;

    // Q fragments (B-operand): col=lc -> Q row rowX+lc, k = ks*32+lr*8+j
    bf16x8 qL[2], qH[2];
#pragma unroll
    for (int ks = 0; ks < 2; ++ks) {
      qL[ks] = *(const bf16x8*)&Q[qbase + (size_t)(rowL + lc) * HD_ + ks * 32 + lr * 8];
      qH[ks] = *(const bf16x8*)&Q[qbase + (size_t)(rowH + lc) * HD_ + ks * 32 + lr * 8];
    }

    f32x4 oL[4] = {}, oH[4] = {};
    float mL = -1e30f, mH = -1e30f, lsL = 0.f, lsH = 0.f;

    auto loadK = [&](bf16x8 (&kf)[2][4], int kv0x) {
#pragma unroll
      for (int ks = 0; ks < 2; ++ks)
#pragma unroll
        for (int ni = 0; ni < 4; ++ni)
          kf[ks][ni] = *(const bf16x8*)&Kt[kbase + (size_t)(kv0x + ni * 16 + lc) * HD_ + ks * 32 + lr * 8];
    };

    // softmax on a raw score tile; updates (m, ls, o), emits PV A-fragments pa
    auto softmax = [&](f32x4 (&s)[4], int kv0, int qrow0, bool diag,
                       float& m, float& ls, f32x4 (&o)[4], bf16x8 (&pa)[2]) {
      if (diag) {
        const int qcol = qrow0 + lc;
#pragma unroll
        for (int ni = 0; ni < 4; ++ni)
#pragma unroll
          for (int r = 0; r < 4; ++r)
            if (kv0 + ni * 16 + lr * 4 + r > qcol) s[ni][r] = -1e30f;
      }
      float x0 = fmaxf(fmaxf(s[0][0], s[0][1]), fmaxf(s[0][2], s[0][3]));
      float x1 = fmaxf(fmaxf(s[1][0], s[1][1]), fmaxf(s[1][2], s[1][3]));
      float x2 = fmaxf(fmaxf(s[2][0], s[2][1]), fmaxf(s[2][2], s[2][3]));
      float x3 = fmaxf(fmaxf(s[3][0], s[3][1]), fmaxf(s[3][2], s[3][3]));
      float pm = fmaxf(fmaxf(x0, x1), fmaxf(x2, x3));
      pm = fmaxf(pm, __shfl_xor(pm, 16));
      pm = fmaxf(pm, __shfl_xor(pm, 32));
      const float pms = pm * SC;
      // defer-max (T13, log2 domain, THR=8)
      if (!__all(pms <= m + 8.f)) {
        float mn = fmaxf(m, pms);
        float al = __builtin_amdgcn_exp2f(m - mn);
        m = mn;
        ls *= al;
        float av0 = __shfl(al, lr * 4 + 0);
        float av1 = __shfl(al, lr * 4 + 1);
        float av2 = __shfl(al, lr * 4 + 2);
        float av3 = __shfl(al, lr * 4 + 3);
#pragma unroll
        for (int di = 0; di < 4; ++di) {
          o[di][0] *= av0; o[di][1] *= av1;
          o[di][2] *= av2; o[di][3] *= av3;
        }
      }
      float ps = 0.f;
      unsigned int P01[4], P23[4];
#pragma unroll
      for (int ni = 0; ni < 4; ++ni) {
        float p0 = __builtin_amdgcn_exp2f(__builtin_fmaf(s[ni][0], SC, -m));
        float p1 = __builtin_amdgcn_exp2f(__builtin_fmaf(s[ni][1], SC, -m));
        float p2 = __builtin_amdgcn_exp2f(__builtin_fmaf(s[ni][2], SC, -m));
        float p3 = __builtin_amdgcn_exp2f(__builtin_fmaf(s[ni][3], SC, -m));
        ps += (p0 + p1) + (p2 + p3);
        P01[ni] = cvt_pk_bf16(p0, p1);
        P23[ni] = cvt_pk_bf16(p2, p3);
      }
      ps += __shfl_xor(ps, 16);
      ps += __shfl_xor(ps, 32);
      ls += ps;
      // regroup: lane(lc,lr) needs K-chunk ks*32+lr*8..+7 of Q-row lc
#pragma unroll
      for (int ks = 0; ks < 2; ++ks) {
        unsigned int a0 = __shfl(P01[2 * ks], srcA);
        unsigned int a1 = __shfl(P23[2 * ks], srcA);
        unsigned int a2 = __shfl(P01[2 * ks], srcA + 16);
        unsigned int a3 = __shfl(P23[2 * ks], srcA + 16);
        unsigned int b0 = __shfl(P01[2 * ks + 1], srcA);
        unsigned int b1 = __shfl(P23[2 * ks + 1], srcA);
        unsigned int b2 = __shfl(P01[2 * ks + 1], srcA + 16);
        unsigned int b3 = __shfl(P23[2 * ks + 1], srcA + 16);
        union { unsigned int u[4]; bf16x8 v; } pw;
        pw.u[0] = hi ? b0 : a0;
        pw.u[1] = hi ? b1 : a1;
        pw.u[2] = hi ? b2 : a2;
        pw.u[3] = hi ? b3 : a3;
        pa[ks] = pw.v;
      }
    };

    bf16x8 kf[2][4];
    loadK(kf, 0);  // prologue

    for (int kvt = 0; kvt <= qhi; ++kvt) {
      const int kv0 = kvt * 64;
      const bool doL = (kvt <= qlo);

      // V fragments issued early — hide under QK + softmax
      bf16x8 vf[2][4];
#pragma unroll
      for (int ks = 0; ks < 2; ++ks)
#pragma unroll
        for (int di = 0; di < 4; ++di)
          vf[ks][di] = *(const bf16x8*)&Vt[vbase + (size_t)(di * 16 + lc) * T_ + kv0 + ks * 32 + lr * 8];

      // QK^T for H fragment (kf prefetched last iteration)
      f32x4 s[4] = {};
      __builtin_amdgcn_s_setprio(1);
#pragma unroll
      for (int ks = 0; ks < 2; ++ks)
#pragma unroll
        for (int ni = 0; ni < 4; ++ni)
          s[ni] = __builtin_amdgcn_mfma_f32_16x16x32_bf16(kf[ks][ni], qH[ks], s[ni], 0, 0, 0);
      __builtin_amdgcn_s_setprio(0);

      bf16x8 paH[2], paL[2];
      softmax(s, kv0, rowH, kvt == qhi, mH, lsH, oH, paH);

      if (doL) {
        f32x4 s2[4] = {};
        __builtin_amdgcn_s_setprio(1);
#pragma unroll
        for (int ks = 0; ks < 2; ++ks)
#pragma unroll
          for (int ni = 0; ni < 4; ++ni)
            s2[ni] = __builtin_amdgcn_mfma_f32_16x16x32_bf16(kf[ks][ni], qL[ks], s2[ni], 0, 0, 0);
        __builtin_amdgcn_s_setprio(0);
        if (kvt < qhi) loadK(kf, kv0 + 64);  // prefetch next K tile
        softmax(s2, kv0, rowL, kvt == qlo, mL, lsL, oL, paL);
      } else {
        if (kvt < qhi) loadK(kf, kv0 + 64);
      }

      // PV
      __builtin_amdgcn_s_setprio(1);
#pragma unroll
      for (int ks = 0; ks < 2; ++ks)
#pragma unroll
        for (int di = 0; di < 4; ++di)
          oH[di] = __builtin_amdgcn_mfma_f32_16x16x32_bf16(paH[ks], vf[ks][di], oH[di], 0, 0, 0);
      if (doL) {
#pragma unroll
        for (int ks = 0; ks < 2; ++ks)
#pragma unroll
          for (int di = 0; di < 4; ++di)
            oL[di] = __builtin_amdgcn_mfma_f32_16x16x32_bf16(paL[ks], vf[ks][di], oL[di], 0, 0, 0);
      }
      __builtin_amdgcn_s_setprio(0);
    }

    // epilogue: rows lr*4+r ; lsum lives lc-indexed in lanes 0..15
    auto epi = [&](f32x4 (&o)[4], float ls, int row0) {
      float i0 = 1.f / __shfl(ls, lr * 4 + 0);
      float i1 = 1.f / __shfl(ls, lr * 4 + 1);
      float i2 = 1.f / __shfl(ls, lr * 4 + 2);
      float i3 = 1.f / __shfl(ls, lr * 4 + 3);
#pragma unroll
      for (int di = 0; di < 4; ++di) {
        int row = row0 + lr * 4;
        size_t base = (size_t)(b * T_ + row) * DIM_ + h * 64 + di * 16 + lc;
        O[base]            = f2bf(o[di][0] * i0);
        O[base + DIM_]     = f2bf(o[di][1] * i1);
        O[base + 2 * DIM_] = f2bf(o[di][2] * i2);
        O[base + 3 * DIM_] = f2bf(o[di][3] * i3);
      }
    };
    epi(oH, lsH, rowH);
    epi(oL, lsL, rowL);
  }
}

// ---------------------------------------------------------------------------
// Orchestration
// ---------------------------------------------------------------------------
extern "C" void kernel_launch(void* const* d_in, const int* in_sizes, int n_in,
                              void* d_out, int out_size, void* d_ws, size_t ws_size,
                              hipStream_t stream) {
  const float* x  = (const float*)d_in[0];
  const float* fc = (const float*)d_in[1];
  const float* fs = (const float*)d_in[2];
  const float* wq = (const float*)d_in[3];
  const float* wk = (const float*)d_in[4];
  const float* wv = (const float*)d_in[5];
  const float* wo = (const float*)d_in[6];
  float* out = (float*)d_out;
  char* ws = (char*)d_ws;

  // workspace layout (bytes)
  unsigned short* xb   = (unsigned short*)(ws);                   // 16 MB  x bf16 [4096][2048]
  unsigned short* wT   = (unsigned short*)(ws + 16777216);        // 12 MB  wqkv^T bf16 [3072][2048]
  unsigned short* woT  = (unsigned short*)(ws + 29360128);        //  8 MB  wo^T bf16 [2048][2048]
  unsigned short* qkvb = (unsigned short*)(ws + 37748736);        // 24 MB  qkv bf16 [4096][3072]
  unsigned short* qb   = (unsigned short*)(ws + 62914560);        // 16 MB  q bf16 [B][H][T][64]
  unsigned short* kb   = (unsigned short*)(ws + 79691776);        //  4 MB  k bf16 [B][HKV][T][64]
  unsigned short* vt   = (unsigned short*)(ws + 83886080);        //  4 MB  v bf16 [B][HKV][64][T]
  unsigned short* attn = qkvb;                                    // alias (dead after vtrans)

  dim3 tb(32, 8);
  k_transpose_w<<<dim3(64, 64), tb, 0, stream>>>(wq, wT, 2048, 2048);
  k_transpose_w<<<dim3(16, 64), tb, 0, stream>>>(wk, wT + (size_t)2048 * 2048, 2048, 512);
  k_transpose_w<<<dim3(16, 64), tb, 0, stream>>>(wv, wT + (size_t)2560 * 2048, 2048, 512);
  k_transpose_w<<<dim3(64, 64), tb, 0, stream>>>(wo, woT, 2048, 2048);
  k_cvt_bf16<<<8192, 256, 0, stream>>>(x, xb, 2097152);

  k_gemm_bt<true><<<dim3(NQKV / 128, 4096 / 128), 256, 0, stream>>>(xb, wT, qkvb, 4096, NQKV, 2048);

  k_rope_q<<<4096, 256, 0, stream>>>(qkvb, fc, fs, qb);
  k_rope_k<<<1024, 256, 0, stream>>>(qkvb, fc, fs, kb);
  k_vtrans<<<dim3(T_ / 64, B_ * HKV_), dim3(64, 4), 0, stream>>>(qkvb, vt);

  k_flash<<<512, 256, 0, stream>>>(qb, kb, vt, attn);

  k_gemm_bt<false><<<dim3(2048 / 128, 4096 / 128), 256, 0, stream>>>(attn, woT, out, 4096, 2048, 2048);
}